// Round 7
// baseline (226.539 us; speedup 1.0000x reference)
//
#include <hip/hip_runtime.h>
#include <hip/hip_bf16.h>

// SchNet CFConv, MI355X gfx950 — round 7.
// vs round 6 (204 us, cfconv 111 us, VALU-issue-bound at ~55% issue eff):
//  * neighbor compaction via thread-0 serial scan (simple, auditable); dead/pad
//    rows become exact zeros everywhere (cm=0 -> H row 0, C-init 0, gather 0)
//  * H chunked to one 16-row tile -> LDS ~9.6 KB -> 8 blocks/CU (32 waves)
//  * biases via MFMA C-init (b1 splat; cm*b2 with cm folded into H rows)
//  * f2out as MFMA (A=Wf2oT bf16, B=y hi/lo split bf16) instead of 150-inst
//    vector loop
//
// d_ws layout (unsigned short elements):
//   [0     .. 4096 )  W1T   bf16 [128 f][32 gpad]
//   [4096  .. 20480)  W2T   bf16 [128 h][128 j]
//   [20480 .. 36864)  WiT   bf16 [128 f][128 i]
//   [36864 .. 53248)  Wf2oT bf16 [128 o][128 i]
//   [53248 .. +1.28M) yfeatb bf16 [10000][128]

#define NA 10000
#define NK 48
#define NF 128
#define DREP 40   // dRe LDS row pad (bf16, 80 B rows)
#define HP   136  // H-chunk LDS row pad (bf16, 272 B rows)

typedef __bf16 bf16x8 __attribute__((ext_vector_type(8)));
typedef float  f32x4  __attribute__((ext_vector_type(4)));

__device__ __forceinline__ unsigned short f2bs(float x) {
    return __builtin_bit_cast(unsigned short, (__bf16)x);
}
__device__ __forceinline__ float bs2f(unsigned short u) {
    return (float)__builtin_bit_cast(__bf16, u);
}
__device__ __forceinline__ float sspf(float v) {
    return fmaxf(v, 0.0f) + __logf(1.0f + __expf(-fabsf(v))) - 0.69314718056f;
}

// ---- K1: transpose-convert weights to bf16 in d_ws (208 blocks) ----
__global__ __launch_bounds__(256) void prep_weights(
    const float* __restrict__ W1,
    const float* __restrict__ W2,
    const float* __restrict__ Wi,
    const float* __restrict__ Wf2o,
    unsigned short* __restrict__ wsb)
{
    int i = blockIdx.x * 256 + threadIdx.x;
    if (i < 4096) {                       // W1T[f][g], g padded to 32
        int f = i >> 5, g = i & 31;
        wsb[i] = (g < 25) ? f2bs(W1[g * NF + f]) : (unsigned short)0;
    } else if (i < 20480) {               // W2T[h][j] = W2[j][h]
        int j = i - 4096; int h = j >> 7, k = j & 127;
        wsb[i] = f2bs(W2[k * NF + h]);
    } else if (i < 36864) {               // WiT[f][i] = Wi[i][f]
        int j = i - 20480; int f = j >> 7, k = j & 127;
        wsb[i] = f2bs(Wi[k * NF + f]);
    } else if (i < 53248) {               // Wf2oT[o][i] = Wf2o[i][o]
        int j = i - 36864; int o = j >> 7, k = j & 127;
        wsb[i] = f2bs(Wf2o[k * NF + o]);
    }
}

// ---- K2: yfeatb = bf16(x @ W_in2f), 625 blocks x 16 rows, WiT from global ----
__global__ __launch_bounds__(256) void in2f_mfma(
    const float* __restrict__ x,
    const unsigned short* __restrict__ WiT,
    unsigned short* __restrict__ yfeatb)
{
    const int tid = threadIdx.x;
    const int w = tid >> 6;
    const int lane = tid & 63;
    const int r = lane & 15;
    const int q = lane >> 4;
    const int nt0 = w * 2;
    const int m0 = blockIdx.x * 16;   // 625*16 = 10000 exact

    bf16x8 a[4];
    #pragma unroll
    for (int ks = 0; ks < 4; ++ks) {
        const float4* xp = (const float4*)(x + (size_t)(m0 + r) * NF + ks * 32 + q * 8);
        float4 v0 = xp[0], v1 = xp[1];
        a[ks][0]=(__bf16)v0.x; a[ks][1]=(__bf16)v0.y; a[ks][2]=(__bf16)v0.z; a[ks][3]=(__bf16)v0.w;
        a[ks][4]=(__bf16)v1.x; a[ks][5]=(__bf16)v1.y; a[ks][6]=(__bf16)v1.z; a[ks][7]=(__bf16)v1.w;
    }

    f32x4 acc0 = (f32x4){0.f,0.f,0.f,0.f};
    f32x4 acc1 = (f32x4){0.f,0.f,0.f,0.f};
    #pragma unroll
    for (int ks = 0; ks < 4; ++ks) {
        bf16x8 b0 = *(const bf16x8*)(WiT + ((nt0    ) * 16 + r) * NF + ks * 32 + q * 8);
        bf16x8 b1 = *(const bf16x8*)(WiT + ((nt0 + 1) * 16 + r) * NF + ks * 32 + q * 8);
        acc0 = __builtin_amdgcn_mfma_f32_16x16x32_bf16(a[ks], b0, acc0, 0, 0, 0);
        acc1 = __builtin_amdgcn_mfma_f32_16x16x32_bf16(a[ks], b1, acc1, 0, 0, 0);
    }
    #pragma unroll
    for (int reg = 0; reg < 4; ++reg) {
        yfeatb[(size_t)(m0 + q * 4 + reg) * NF + (nt0    ) * 16 + r] = f2bs(acc0[reg]);
        yfeatb[(size_t)(m0 + q * 4 + reg) * NF + (nt0 + 1) * 16 + r] = f2bs(acc1[reg]);
    }
}

// ---- K3: cfconv, 1 atom/block, compaction + chunked H + MFMA f2out ----
__global__ __launch_bounds__(256) void cfconv_mfma(
    const float* __restrict__ dR,
    const float* __restrict__ dRe,
    const float* __restrict__ mask,
    const int*   __restrict__ nbr,
    const float* __restrict__ b1,
    const float* __restrict__ b2,
    const float* __restrict__ bf2o,
    const unsigned short* __restrict__ W1T,
    const unsigned short* __restrict__ W2T,
    const unsigned short* __restrict__ Wf2oT,
    const unsigned short* __restrict__ yfeatb,
    float* __restrict__ out)
{
    __shared__ __align__(16) unsigned short s_dre[NK * DREP]; // 3840 B
    __shared__ __align__(16) unsigned short s_Hc[16 * HP];    // 4352 B (one 16-row tile)
    __shared__ __align__(16) unsigned short s_ybh[NF];        // y hi bf16
    __shared__ __align__(16) unsigned short s_ybl[NF];        // y lo bf16
    __shared__ __align__(16) float s_cmc[NK];
    __shared__ __align__(16) int   s_nbc[NK];
    __shared__ float s_cm[NK];
    __shared__ int   s_nb[NK];
    __shared__ int   s_ci[NK];
    __shared__ int   s_kc;

    const int tid = threadIdx.x;
    const int n = blockIdx.x;
    const int w = tid >> 6;
    const int lane = tid & 63;
    const int r = lane & 15;
    const int q = lane >> 4;
    const int nt0 = w * 2;
    const int h0i = nt0 * 16 + r;

    // ---- phase 0: zero dre, load raw cm/nb ----
    {
        unsigned int* z = (unsigned int*)s_dre;
        for (int i = tid; i < NK * DREP / 2; i += 256) z[i] = 0u;
    }
    if (tid < NK) {
        float d = dR[n * NK + tid];
        float m = mask[n * NK + tid];
        s_cm[tid] = (d <= 5.0f) ? m : 0.0f;
        s_nb[tid] = nbr[n * NK + tid] * NF;
    }
    __syncthreads();

    // ---- phase 1: thread-0 serial compaction scan (trivially ordered) ----
    if (tid == 0) {
        int j = 0;
        for (int k = 0; k < NK; ++k) {
            float c = s_cm[k];
            if (c != 0.0f) { s_ci[j] = k; s_cmc[j] = c; s_nbc[j] = s_nb[k]; ++j; }
        }
        s_kc = j;
        for (int k = j; k < NK; ++k) { s_cmc[k] = 0.0f; s_nbc[k] = 0; }
    }
    // weight fragments + biases (global, no LDS dependency)
    const float bias1a = b1[h0i];
    const float bias1b = b1[h0i + 16];
    const float bias2a = b2[h0i];
    const float bias2b = b2[h0i + 16];
    bf16x8 bfr0 = *(const bf16x8*)(W1T + ((nt0    ) * 16 + r) * 32 + q * 8);
    bf16x8 bfr1 = *(const bf16x8*)(W1T + ((nt0 + 1) * 16 + r) * 32 + q * 8);
    bf16x8 bw[2][4];
    #pragma unroll
    for (int t = 0; t < 2; ++t)
        #pragma unroll
        for (int ks = 0; ks < 4; ++ks)
            bw[t][ks] = *(const bf16x8*)(W2T + ((nt0 + t) * 16 + r) * NF + ks * 32 + q * 8);
    __syncthreads();

    const int kc = s_kc;
    const int mtiles = (kc + 15) >> 4;   // 0..3, typically 2

    // ---- phase 2: stage compacted dRe rows (rows >= kc stay zero) ----
    {
        const float* dre = dRe + (size_t)n * (NK * 25);
        int tot = kc * 25;
        for (int i = tid; i < tot; i += 256) {
            int kidx = (int)((unsigned)i / 25u);
            int g = i - kidx * 25;
            s_dre[kidx * DREP + g] = f2bs(dre[s_ci[kidx] * 25 + g]);
        }
    }
    __syncthreads();

    // ---- per-tile: stage1 -> barrier -> stage2 + gather -> barrier ----
    float part0 = 0.f, part1 = 0.f;
    for (int mt = 0; mt < mtiles; ++mt) {
        const float* cmp = &s_cmc[mt * 16 + q * 4];
        const int*   nbp = &s_nbc[mt * 16 + q * 4];
        float cm0 = cmp[0], cm1 = cmp[1], cm2 = cmp[2], cm3 = cmp[3];

        // stage 1: Hrow = cm[k] * ssp(dRe_c @ W1 + b1)   (C-init = b1 splat)
        bf16x8 af = *(const bf16x8*)(&s_dre[(mt * 16 + r) * DREP + q * 8]);
        f32x4 h0 = __builtin_amdgcn_mfma_f32_16x16x32_bf16(
            af, bfr0, (f32x4){bias1a, bias1a, bias1a, bias1a}, 0, 0, 0);
        f32x4 h1 = __builtin_amdgcn_mfma_f32_16x16x32_bf16(
            af, bfr1, (f32x4){bias1b, bias1b, bias1b, bias1b}, 0, 0, 0);
        s_Hc[(q * 4 + 0) * HP + h0i]      = f2bs(sspf(h0[0]) * cm0);
        s_Hc[(q * 4 + 1) * HP + h0i]      = f2bs(sspf(h0[1]) * cm1);
        s_Hc[(q * 4 + 2) * HP + h0i]      = f2bs(sspf(h0[2]) * cm2);
        s_Hc[(q * 4 + 3) * HP + h0i]      = f2bs(sspf(h0[3]) * cm3);
        s_Hc[(q * 4 + 0) * HP + h0i + 16] = f2bs(sspf(h1[0]) * cm0);
        s_Hc[(q * 4 + 1) * HP + h0i + 16] = f2bs(sspf(h1[1]) * cm1);
        s_Hc[(q * 4 + 2) * HP + h0i + 16] = f2bs(sspf(h1[2]) * cm2);
        s_Hc[(q * 4 + 3) * HP + h0i + 16] = f2bs(sspf(h1[3]) * cm3);
        __syncthreads();

        // stage 2: A2c = Hc @ W2, C-init = cm*b2  (rows pre-scaled by cm)
        f32x4 acc0 = (f32x4){cm0 * bias2a, cm1 * bias2a, cm2 * bias2a, cm3 * bias2a};
        f32x4 acc1 = (f32x4){cm0 * bias2b, cm1 * bias2b, cm2 * bias2b, cm3 * bias2b};
        #pragma unroll
        for (int ks = 0; ks < 4; ++ks) {
            bf16x8 ah = *(const bf16x8*)(&s_Hc[r * HP + ks * 32 + q * 8]);
            acc0 = __builtin_amdgcn_mfma_f32_16x16x32_bf16(ah, bw[0][ks], acc0, 0, 0, 0);
            acc1 = __builtin_amdgcn_mfma_f32_16x16x32_bf16(ah, bw[1][ks], acc1, 0, 0, 0);
        }

        // gather: part += A2c[k][h] * yfeat[nbr[k]][h]
        #pragma unroll
        for (int reg = 0; reg < 4; ++reg) {
            int base = nbp[reg];
            part0 = fmaf(acc0[reg], bs2f(yfeatb[base + h0i]),      part0);
            part1 = fmaf(acc1[reg], bs2f(yfeatb[base + h0i + 16]), part1);
        }
        __syncthreads();   // Hc reused next tile
    }

    // ---- reduce over q; write y as hi/lo bf16 for MFMA f2out ----
    part0 += __shfl_xor(part0, 16);
    part0 += __shfl_xor(part0, 32);
    part1 += __shfl_xor(part1, 16);
    part1 += __shfl_xor(part1, 32);
    if (q == 0) {
        unsigned short hh0 = f2bs(part0);
        unsigned short hh1 = f2bs(part1);
        s_ybh[h0i]      = hh0;
        s_ybl[h0i]      = f2bs(part0 - bs2f(hh0));
        s_ybh[h0i + 16] = hh1;
        s_ybl[h0i + 16] = f2bs(part1 - bs2f(hh1));
    }
    __syncthreads();

    // ---- f2out via MFMA: out = ssp(Wf2oT @ (yh + yl) + bf2o) ----
    {
        bf16x8 ybh[4], ybl[4];
        #pragma unroll
        for (int ks = 0; ks < 4; ++ks) {
            ybh[ks] = *(const bf16x8*)(&s_ybh[ks * 32 + q * 8]);   // broadcast
            ybl[ks] = *(const bf16x8*)(&s_ybl[ks * 32 + q * 8]);
        }
        #pragma unroll
        for (int t = 0; t < 2; ++t) {
            int mt = nt0 + t;
            f32x4 acc = *(const f32x4*)(bf2o + mt * 16 + q * 4);   // C-init = bias
            #pragma unroll
            for (int ks = 0; ks < 4; ++ks) {
                bf16x8 afw = *(const bf16x8*)(Wf2oT + (mt * 16 + r) * NF + ks * 32 + q * 8);
                acc = __builtin_amdgcn_mfma_f32_16x16x32_bf16(afw, ybh[ks], acc, 0, 0, 0);
                acc = __builtin_amdgcn_mfma_f32_16x16x32_bf16(afw, ybl[ks], acc, 0, 0, 0);
            }
            if (r == 0) {   // all 16 cols identical; lanes r==0 store rows
                #pragma unroll
                for (int reg = 0; reg < 4; ++reg)
                    out[(size_t)n * NF + mt * 16 + q * 4 + reg] = sspf(acc[reg]);
            }
        }
    }
}

extern "C" void kernel_launch(void* const* d_in, const int* in_sizes, int n_in,
                              void* d_out, int out_size, void* d_ws, size_t ws_size,
                              hipStream_t stream)
{
    const float* x    = (const float*)d_in[0];
    const float* dR   = (const float*)d_in[1];
    const float* dRe  = (const float*)d_in[2];
    const float* mask = (const float*)d_in[3];
    const int*   nbr  = (const int*)d_in[4];
    const float* W1   = (const float*)d_in[5];
    const float* b1   = (const float*)d_in[6];
    const float* W2   = (const float*)d_in[7];
    const float* b2   = (const float*)d_in[8];
    const float* Wi2f = (const float*)d_in[9];
    const float* Wf2o = (const float*)d_in[10];
    const float* bf2o = (const float*)d_in[11];
    float* out = (float*)d_out;

    unsigned short* wsb = (unsigned short*)d_ws;
    unsigned short* W1T    = wsb;            // 4096
    unsigned short* W2T    = wsb + 4096;     // 16384
    unsigned short* WiT    = wsb + 20480;    // 16384
    unsigned short* Wf2oT  = wsb + 36864;    // 16384
    unsigned short* yfeatb = wsb + 53248;    // 1,280,000

    prep_weights<<<208, 256, 0, stream>>>(W1, W2, Wi2f, Wf2o, wsb);
    in2f_mfma<<<625, 256, 0, stream>>>(x, WiT, yfeatb);
    cfconv_mfma<<<NA, 256, 0, stream>>>(dR, dRe, mask, nbr, b1, b2, bf2o,
                                        W1T, W2T, Wf2oT, yfeatb, out);
}